// Round 17
// baseline (205.167 us; speedup 1.0000x reference)
//
#include <hip/hip_runtime.h>

#define IMG_H 768
#define IMG_W 768
#define N_IMG 32
#define TILE 64
#define HALO 2
#define LW 68              // 64 + 2*HALO
#define INV_LOG2 1.44269504088896340736f
#define TILES_X 12
#define TILES_PER_IMG 144
#define NTILES (N_IMG * TILES_PER_IMG)   // 4608

__device__ __forceinline__ float fast_sigmoid(float y) {
    return 1.0f / (1.0f + __expf(-y));
}

// Slide: add incoming pbuf row, subtract outgoing pbuf row (V1/V2 window).
#define SLIDE(rr)                                                              \
    do {                                                                       \
        const float* rin  = &pbuf[((rr) + 5) * LW + c0];                       \
        const float* rout = &pbuf[(rr) * LW + c0];                             \
        float4 IA = *reinterpret_cast<const float4*>(rin);                     \
        float4 IB = *reinterpret_cast<const float4*>(rin + 4);                 \
        float4 OA = *reinterpret_cast<const float4*>(rout);                    \
        float4 OB = *reinterpret_cast<const float4*>(rout + 4);                \
        float vin[8]  = {IA.x, IA.y, IA.z, IA.w, IB.x, IB.y, IB.z, IB.w};      \
        float vout[8] = {OA.x, OA.y, OA.z, OA.w, OB.x, OB.y, OB.z, OB.w};      \
        _Pragma("unroll")                                                      \
        for (int cc = 0; cc < 8; ++cc) {                                       \
            V1[cc] += vin[cc] - vout[cc];                                      \
            V2[cc] += fmaf(vin[cc], vin[cc], -(vout[cc] * vout[cc]));          \
        }                                                                      \
    } while (0)

// Incremental horizontal 5-window sums from 8 column sums (10 adds each).
#define HSUMS(S, V)                                                            \
    float S[4];                                                                \
    S[0] = ((V[0] + V[1]) + (V[2] + V[3])) + V[4];                             \
    S[1] = S[0] - V[0] + V[5];                                                 \
    S[2] = S[1] - V[1] + V[6];                                                 \
    S[3] = S[2] - V[2] + V[7];

// Pass 1: r15 body (best, 71.8 us). Per-WAVE partial stores (no atomics —
// the 32-float sums[] line was a device-wide serialization point, r14; no
// LDS reduce / tail barrier either). launch_bounds pins VGPR <= 64: the
// session's hard law is that wave-residency dominates (r11/r16 regressions).
__global__ __launch_bounds__(256, 8) void wk_pass1(
    const float* __restrict__ y_d, const float* __restrict__ y_gt,
    float* __restrict__ out, float* __restrict__ partials)
{
    __shared__ float pbuf[LW * LW];   // 18.5 KB

    const int b = blockIdx.x;
    const int img = b / TILES_PER_IMG;
    const int t = b - img * TILES_PER_IMG;
    const int ti = t / TILES_X;
    const int tj = t - ti * TILES_X;
    const int gi0 = ti * TILE, gj0 = tj * TILE;
    const bool interior = ((unsigned)(ti - 1) < 10u) && ((unsigned)(tj - 1) < 10u);

    const size_t img_off = (size_t)img * IMG_H * IMG_W;
    const float* __restrict__ yimg = y_d + img_off;
    const float* __restrict__ gimg = y_gt + img_off;
    float* __restrict__ oimg = out + img_off;

    const int tid = threadIdx.x;
    const int c0 = (tid & 15) << 2;    // tile col base 0..60
    const int rb = (tid >> 4) << 2;    // tile row base 0..60
    const int gj = gj0 + c0;

    // ---- stage own 4x4 block: p -> LDS, ent -> regs ----
    // ent = 1 + (p*y - softplus(y))/ln2; softplus shares the exp with sigmoid.
    float4 ev4[4];
#pragma unroll
    for (int r = 0; r < 4; ++r) {
        float4 y4 = *reinterpret_cast<const float4*>(
            &yimg[(size_t)(gi0 + rb + r) * IMG_W + gj]);
        float yy[4] = {y4.x, y4.y, y4.z, y4.w};
        float pp[4], ee[4];
#pragma unroll
        for (int u = 0; u < 4; ++u) {
            float y  = yy[u];
            float E  = __expf(-fabsf(y));
            float t2 = 1.0f + E;
            float rr = __fdividef(1.0f, t2);
            float p  = (y >= 0.0f) ? rr : E * rr;
            float sp = fmaxf(y, 0.0f) + __logf(t2);
            pp[u] = p;
            ee[u] = fmaf(fmaf(p, y, -sp), INV_LOG2, 1.0f);
        }
        *reinterpret_cast<float4*>(&pbuf[(rb + HALO + r) * LW + (c0 + HALO)]) =
            make_float4(pp[0], pp[1], pp[2], pp[3]);
        ev4[r] = make_float4(ee[0], ee[1], ee[2], ee[3]);
    }

    // ---- halo, p only: rows {0,1,66,67} x 68 cols (272) + cols {0,1,66,67}
    // x rows 2..65 (256) = 528. Interior tiles: unguarded (all in-bounds).
    // Border tiles: OOB -> p = 0.0 (the C-1 normalization relies on this).
    for (int idx = tid; idx < 528; idx += 256) {
        int pr, pc;
        if (idx < 272) {
            int rsel = idx / 68;
            pr = (rsel < 2) ? rsel : (64 + rsel);    // 0,1,66,67
            pc = idx - rsel * 68;
        } else {
            int k = idx - 272;
            pr = (k >> 2) + 2;                       // 2..65
            int h = k & 3;
            pc = (h < 2) ? h : (64 + h);             // 0,1,66,67
        }
        int gi_ = gi0 - HALO + pr;
        int gj_ = gj0 - HALO + pc;
        float p;
        if (interior) {
            p = fast_sigmoid(yimg[(size_t)gi_ * IMG_W + gj_]);
        } else {
            p = 0.0f;
            if ((unsigned)gi_ < (unsigned)IMG_H && (unsigned)gj_ < (unsigned)IMG_W)
                p = fast_sigmoid(yimg[(size_t)gi_ * IMG_W + gj_]);
        }
        pbuf[pr * LW + pc] = p;
    }
    __syncthreads();

    // ---- vertical 5-row column sums for pbuf cols c0..c0+7 ----
    float V1[8], V2[8];
#pragma unroll
    for (int cc = 0; cc < 8; ++cc) { V1[cc] = 0.f; V2[cc] = 0.f; }
#pragma unroll
    for (int k = 0; k < 5; ++k) {
        const float* row = &pbuf[(rb + k) * LW + c0];
        float4 A = *reinterpret_cast<const float4*>(row);
        float4 B = *reinterpret_cast<const float4*>(row + 4);
        float a[8] = {A.x, A.y, A.z, A.w, B.x, B.y, B.z, B.w};
#pragma unroll
        for (int cc = 0; cc < 8; ++cc) {
            V1[cc] += a[cc];
            V2[cc] = fmaf(a[cc], a[cc], V2[cc]);
        }
    }

    float lsum = 0.0f;

    if (interior) {
        const float RC = 1.0f / 24.0f;
#pragma unroll
        for (int r = 0; r < 4; ++r) {
            const int gi = gi0 + rb + r;
            float4 g4 = *reinterpret_cast<const float4*>(
                &gimg[(size_t)gi * IMG_W + gj]);
            const float* crow = &pbuf[(rb + r + 2) * LW + (c0 + 2)];
            float2 pA = *reinterpret_cast<const float2*>(crow);
            float2 pB = *reinterpret_cast<const float2*>(crow + 2);
            float pcv[4] = {pA.x, pA.y, pB.x, pB.y};

            HSUMS(S1v, V1)
            HSUMS(S2v, V2)

            float ev[4] = {ev4[r].x, ev4[r].y, ev4[r].z, ev4[r].w};
            float gv[4] = {g4.x, g4.y, g4.z, g4.w};
            float wv[4];
#pragma unroll
            for (int c = 0; c < 4; ++c) {
                float pc = pcv[c];
                float acc = fmaf(25.0f * pc, pc, fmaf(-2.0f * pc, S1v[c], S2v[c]));
                float cons = fmaf(-acc, RC, 1.0f);
                float w = fmaxf(cons * ev[c], gv[c]);
                w = fmaf(w, 0.9f, 0.1f);
                wv[c] = w;
                lsum += w;
            }
            *reinterpret_cast<float4*>(&oimg[(size_t)gi * IMG_W + gj]) =
                make_float4(wv[0], wv[1], wv[2], wv[3]);
            if (r < 3) SLIDE(rb + r);
        }
    } else {
        float cxv[4];
#pragma unroll
        for (int c = 0; c < 4; ++c) {
            int g = gj + c;
            cxv[c] = (float)(min(g, HALO) + min(IMG_W - 1 - g, HALO) + 1);
        }
#pragma unroll
        for (int r = 0; r < 4; ++r) {
            const int gi = gi0 + rb + r;
            float4 g4 = *reinterpret_cast<const float4*>(
                &gimg[(size_t)gi * IMG_W + gj]);
            const float* crow = &pbuf[(rb + r + 2) * LW + (c0 + 2)];
            float2 pA = *reinterpret_cast<const float2*>(crow);
            float2 pB = *reinterpret_cast<const float2*>(crow + 2);
            float pcv[4] = {pA.x, pA.y, pB.x, pB.y};

            HSUMS(S1v, V1)
            HSUMS(S2v, V2)

            float cy = (float)(min(gi, HALO) + min(IMG_H - 1 - gi, HALO) + 1);
            float ev[4] = {ev4[r].x, ev4[r].y, ev4[r].z, ev4[r].w};
            float gv[4] = {g4.x, g4.y, g4.z, g4.w};
            float wv[4];
#pragma unroll
            for (int c = 0; c < 4; ++c) {
                float pc = pcv[c];
                float C = cy * cxv[c];
                float rc = __fdividef(1.0f, C - 1.0f);
                float acc = fmaf(C * pc, pc, fmaf(-2.0f * pc, S1v[c], S2v[c]));
                float cons = fmaf(-acc, rc, 1.0f);
                float w = fmaxf(cons * ev[c], gv[c]);
                w = fmaf(w, 0.9f, 0.1f);
                wv[c] = w;
                lsum += w;
            }
            *reinterpret_cast<float4*>(&oimg[(size_t)gi * IMG_W + gj]) =
                make_float4(wv[0], wv[1], wv[2], wv[3]);
            if (r < 3) SLIDE(rb + r);
        }
    }

    // ---- per-wave partial: shfl-reduce -> plain store (no barrier/LDS) ----
#pragma unroll
    for (int off = 32; off > 0; off >>= 1)
        lsum += __shfl_down(lsum, off, 64);
    if ((tid & 63) == 0)
        partials[b * 4 + (tid >> 6)] = lsum;
}

// Reduce: one block per image folds its 576 wave partials (9 per lane).
__global__ __launch_bounds__(64) void wk_reduce(
    const float* __restrict__ partials, float* __restrict__ sums)
{
    const int img  = blockIdx.x;
    const int lane = threadIdx.x;
    const float* p = partials + img * TILES_PER_IMG * 4;   // 576
    float s = 0.0f;
#pragma unroll
    for (int k = 0; k < 9; ++k)
        s += p[lane + k * 64];
#pragma unroll
    for (int off = 32; off > 0; off >>= 1)
        s += __shfl_down(s, off, 64);
    if (lane == 0) sums[img] = s;
}

// Pass 2: divide by per-image mean.
__global__ __launch_bounds__(256) void wk_pass2(
    float* __restrict__ out, const float* __restrict__ sums)
{
    const size_t total4 = (size_t)N_IMG * IMG_H * IMG_W / 4;
    const int per_img4 = IMG_H * IMG_W / 4;   // 147456
    for (size_t i = (size_t)blockIdx.x * blockDim.x + threadIdx.x; i < total4;
         i += (size_t)gridDim.x * blockDim.x) {
        int img = (int)(i / per_img4);
        float scale = (float)(IMG_H * IMG_W) / sums[img];
        float4 v = reinterpret_cast<float4*>(out)[i];
        v.x *= scale; v.y *= scale; v.z *= scale; v.w *= scale;
        reinterpret_cast<float4*>(out)[i] = v;
    }
}

extern "C" void kernel_launch(void* const* d_in, const int* in_sizes, int n_in,
                              void* d_out, int out_size, void* d_ws, size_t ws_size,
                              hipStream_t stream) {
    const float* y_d  = (const float*)d_in[0];
    const float* y_gt = (const float*)d_in[1];
    float* out      = (float*)d_out;
    float* partials = (float*)d_ws;               // [NTILES*4]
    float* sums     = partials + NTILES * 4;      // [N_IMG]

    wk_pass1<<<dim3(NTILES), dim3(256), 0, stream>>>(y_d, y_gt, out, partials);
    wk_reduce<<<dim3(N_IMG), dim3(64), 0, stream>>>(partials, sums);
    wk_pass2<<<dim3(2048), dim3(256), 0, stream>>>(out, sums);
}

// Round 18
// 77.947 us; speedup vs baseline: 2.6321x; 2.6321x over previous
//
#include <hip/hip_runtime.h>

#define IMG_H 768
#define IMG_W 768
#define N_IMG 32
#define TILE 64
#define HALO 2
#define LW 68              // 64 + 2*HALO
#define INV_LOG2 1.44269504088896340736f
#define TILES_X 12
#define TILES_PER_IMG 144
#define NTILES (N_IMG * TILES_PER_IMG)   // 4608

__device__ __forceinline__ float fast_sigmoid(float y) {
    return 1.0f / (1.0f + __expf(-y));
}

// Slide: add incoming pbuf row, subtract outgoing pbuf row (V1/V2 window).
#define SLIDE(rr)                                                              \
    do {                                                                       \
        const float* rin  = &pbuf[((rr) + 5) * LW + c0];                       \
        const float* rout = &pbuf[(rr) * LW + c0];                             \
        float4 IA = *reinterpret_cast<const float4*>(rin);                     \
        float4 IB = *reinterpret_cast<const float4*>(rin + 4);                 \
        float4 OA = *reinterpret_cast<const float4*>(rout);                    \
        float4 OB = *reinterpret_cast<const float4*>(rout + 4);                \
        float vin[8]  = {IA.x, IA.y, IA.z, IA.w, IB.x, IB.y, IB.z, IB.w};      \
        float vout[8] = {OA.x, OA.y, OA.z, OA.w, OB.x, OB.y, OB.z, OB.w};      \
        _Pragma("unroll")                                                      \
        for (int cc = 0; cc < 8; ++cc) {                                       \
            V1[cc] += vin[cc] - vout[cc];                                      \
            V2[cc] += fmaf(vin[cc], vin[cc], -(vout[cc] * vout[cc]));          \
        }                                                                      \
    } while (0)

// Incremental horizontal 5-window sums from 8 column sums (10 adds each).
#define HSUMS(S, V)                                                            \
    float S[4];                                                                \
    S[0] = ((V[0] + V[1]) + (V[2] + V[3])) + V[4];                             \
    S[1] = S[0] - V[0] + V[5];                                                 \
    S[2] = S[1] - V[1] + V[6];                                                 \
    S[3] = S[2] - V[2] + V[7];

// Pass 1 (round-15 configuration — measured best: pass1 71.8 us, VGPR 64).
// Per-block partial sums via plain stores; NO atomics (the 32-float sums[]
// line was a device-wide serialization point: r1/r9/r14 all ~210-220 us).
// NO launch_bounds min-waves hint (r17: it pinned VGPR to 32 -> 443 MB of
// scratch spills). NO extra register caching (r11/r16: VGPR>64 kills
// residency, which dominates this kernel).
__global__ __launch_bounds__(256) void wk_pass1(
    const float* __restrict__ y_d, const float* __restrict__ y_gt,
    float* __restrict__ out, float* __restrict__ partials)
{
    __shared__ float pbuf[LW * LW];   // 18.5 KB
    __shared__ float red[4];

    const int b = blockIdx.x;
    const int img = b / TILES_PER_IMG;
    const int t = b - img * TILES_PER_IMG;
    const int ti = t / TILES_X;
    const int tj = t - ti * TILES_X;
    const int gi0 = ti * TILE, gj0 = tj * TILE;
    const bool interior = ((unsigned)(ti - 1) < 10u) && ((unsigned)(tj - 1) < 10u);

    const size_t img_off = (size_t)img * IMG_H * IMG_W;
    const float* __restrict__ yimg = y_d + img_off;
    const float* __restrict__ gimg = y_gt + img_off;
    float* __restrict__ oimg = out + img_off;

    const int tid = threadIdx.x;
    const int c0 = (tid & 15) << 2;    // tile col base 0..60
    const int rb = (tid >> 4) << 2;    // tile row base 0..60
    const int gj = gj0 + c0;

    // ---- stage own 4x4 block: p -> LDS, ent -> regs ----
    // ent = 1 + (p*y - softplus(y))/ln2; softplus shares the exp with sigmoid.
    float4 ev4[4];
#pragma unroll
    for (int r = 0; r < 4; ++r) {
        float4 y4 = *reinterpret_cast<const float4*>(
            &yimg[(size_t)(gi0 + rb + r) * IMG_W + gj]);
        float yy[4] = {y4.x, y4.y, y4.z, y4.w};
        float pp[4], ee[4];
#pragma unroll
        for (int u = 0; u < 4; ++u) {
            float y  = yy[u];
            float E  = __expf(-fabsf(y));
            float t2 = 1.0f + E;
            float rr = __fdividef(1.0f, t2);
            float p  = (y >= 0.0f) ? rr : E * rr;
            float sp = fmaxf(y, 0.0f) + __logf(t2);
            pp[u] = p;
            ee[u] = fmaf(fmaf(p, y, -sp), INV_LOG2, 1.0f);
        }
        *reinterpret_cast<float4*>(&pbuf[(rb + HALO + r) * LW + (c0 + HALO)]) =
            make_float4(pp[0], pp[1], pp[2], pp[3]);
        ev4[r] = make_float4(ee[0], ee[1], ee[2], ee[3]);
    }

    // ---- halo, p only: rows {0,1,66,67} x 68 cols (272) + cols {0,1,66,67}
    // x rows 2..65 (256) = 528. Interior tiles: unguarded (all in-bounds).
    // Border tiles: OOB -> p = 0.0 (the C-1 normalization relies on this).
    for (int idx = tid; idx < 528; idx += 256) {
        int pr, pc;
        if (idx < 272) {
            int rsel = idx / 68;
            pr = (rsel < 2) ? rsel : (64 + rsel);    // 0,1,66,67
            pc = idx - rsel * 68;
        } else {
            int k = idx - 272;
            pr = (k >> 2) + 2;                       // 2..65
            int h = k & 3;
            pc = (h < 2) ? h : (64 + h);             // 0,1,66,67
        }
        int gi_ = gi0 - HALO + pr;
        int gj_ = gj0 - HALO + pc;
        float p;
        if (interior) {
            p = fast_sigmoid(yimg[(size_t)gi_ * IMG_W + gj_]);
        } else {
            p = 0.0f;
            if ((unsigned)gi_ < (unsigned)IMG_H && (unsigned)gj_ < (unsigned)IMG_W)
                p = fast_sigmoid(yimg[(size_t)gi_ * IMG_W + gj_]);
        }
        pbuf[pr * LW + pc] = p;
    }
    __syncthreads();

    // ---- vertical 5-row column sums for pbuf cols c0..c0+7 ----
    float V1[8], V2[8];
#pragma unroll
    for (int cc = 0; cc < 8; ++cc) { V1[cc] = 0.f; V2[cc] = 0.f; }
#pragma unroll
    for (int k = 0; k < 5; ++k) {
        const float* row = &pbuf[(rb + k) * LW + c0];
        float4 A = *reinterpret_cast<const float4*>(row);
        float4 B = *reinterpret_cast<const float4*>(row + 4);
        float a[8] = {A.x, A.y, A.z, A.w, B.x, B.y, B.z, B.w};
#pragma unroll
        for (int cc = 0; cc < 8; ++cc) {
            V1[cc] += a[cc];
            V2[cc] = fmaf(a[cc], a[cc], V2[cc]);
        }
    }

    float lsum = 0.0f;

    if (interior) {
        const float RC = 1.0f / 24.0f;
#pragma unroll
        for (int r = 0; r < 4; ++r) {
            const int gi = gi0 + rb + r;
            float4 g4 = *reinterpret_cast<const float4*>(
                &gimg[(size_t)gi * IMG_W + gj]);
            const float* crow = &pbuf[(rb + r + 2) * LW + (c0 + 2)];
            float2 pA = *reinterpret_cast<const float2*>(crow);
            float2 pB = *reinterpret_cast<const float2*>(crow + 2);
            float pcv[4] = {pA.x, pA.y, pB.x, pB.y};

            HSUMS(S1v, V1)
            HSUMS(S2v, V2)

            float ev[4] = {ev4[r].x, ev4[r].y, ev4[r].z, ev4[r].w};
            float gv[4] = {g4.x, g4.y, g4.z, g4.w};
            float wv[4];
#pragma unroll
            for (int c = 0; c < 4; ++c) {
                float pc = pcv[c];
                float acc = fmaf(25.0f * pc, pc, fmaf(-2.0f * pc, S1v[c], S2v[c]));
                float cons = fmaf(-acc, RC, 1.0f);
                float w = fmaxf(cons * ev[c], gv[c]);
                w = fmaf(w, 0.9f, 0.1f);
                wv[c] = w;
                lsum += w;
            }
            *reinterpret_cast<float4*>(&oimg[(size_t)gi * IMG_W + gj]) =
                make_float4(wv[0], wv[1], wv[2], wv[3]);
            if (r < 3) SLIDE(rb + r);
        }
    } else {
        float cxv[4];
#pragma unroll
        for (int c = 0; c < 4; ++c) {
            int g = gj + c;
            cxv[c] = (float)(min(g, HALO) + min(IMG_W - 1 - g, HALO) + 1);
        }
#pragma unroll
        for (int r = 0; r < 4; ++r) {
            const int gi = gi0 + rb + r;
            float4 g4 = *reinterpret_cast<const float4*>(
                &gimg[(size_t)gi * IMG_W + gj]);
            const float* crow = &pbuf[(rb + r + 2) * LW + (c0 + 2)];
            float2 pA = *reinterpret_cast<const float2*>(crow);
            float2 pB = *reinterpret_cast<const float2*>(crow + 2);
            float pcv[4] = {pA.x, pA.y, pB.x, pB.y};

            HSUMS(S1v, V1)
            HSUMS(S2v, V2)

            float cy = (float)(min(gi, HALO) + min(IMG_H - 1 - gi, HALO) + 1);
            float ev[4] = {ev4[r].x, ev4[r].y, ev4[r].z, ev4[r].w};
            float gv[4] = {g4.x, g4.y, g4.z, g4.w};
            float wv[4];
#pragma unroll
            for (int c = 0; c < 4; ++c) {
                float pc = pcv[c];
                float C = cy * cxv[c];
                float rc = __fdividef(1.0f, C - 1.0f);
                float acc = fmaf(C * pc, pc, fmaf(-2.0f * pc, S1v[c], S2v[c]));
                float cons = fmaf(-acc, rc, 1.0f);
                float w = fmaxf(cons * ev[c], gv[c]);
                w = fmaf(w, 0.9f, 0.1f);
                wv[c] = w;
                lsum += w;
            }
            *reinterpret_cast<float4*>(&oimg[(size_t)gi * IMG_W + gj]) =
                make_float4(wv[0], wv[1], wv[2], wv[3]);
            if (r < 3) SLIDE(rb + r);
        }
    }

    // ---- block partial: wave shfl-reduce -> LDS -> plain store ----
#pragma unroll
    for (int off = 32; off > 0; off >>= 1)
        lsum += __shfl_down(lsum, off, 64);
    if ((tid & 63) == 0) red[tid >> 6] = lsum;
    __syncthreads();
    if (tid == 0)
        partials[b] = (red[0] + red[1]) + (red[2] + red[3]);
}

// Reduce: one block per image folds its 144 tile partials (144 = 64+64+16).
__global__ __launch_bounds__(64) void wk_reduce(
    const float* __restrict__ partials, float* __restrict__ sums)
{
    const int img  = blockIdx.x;
    const int lane = threadIdx.x;
    const float* p = partials + img * TILES_PER_IMG;
    float s = p[lane] + p[lane + 64];
    if (lane < 16) s += p[lane + 128];
#pragma unroll
    for (int off = 32; off > 0; off >>= 1)
        s += __shfl_down(s, off, 64);
    if (lane == 0) sums[img] = s;
}

// Pass 2: divide by per-image mean.
__global__ __launch_bounds__(256) void wk_pass2(
    float* __restrict__ out, const float* __restrict__ sums)
{
    const size_t total4 = (size_t)N_IMG * IMG_H * IMG_W / 4;
    const int per_img4 = IMG_H * IMG_W / 4;   // 147456
    for (size_t i = (size_t)blockIdx.x * blockDim.x + threadIdx.x; i < total4;
         i += (size_t)gridDim.x * blockDim.x) {
        int img = (int)(i / per_img4);
        float scale = (float)(IMG_H * IMG_W) / sums[img];
        float4 v = reinterpret_cast<float4*>(out)[i];
        v.x *= scale; v.y *= scale; v.z *= scale; v.w *= scale;
        reinterpret_cast<float4*>(out)[i] = v;
    }
}

extern "C" void kernel_launch(void* const* d_in, const int* in_sizes, int n_in,
                              void* d_out, int out_size, void* d_ws, size_t ws_size,
                              hipStream_t stream) {
    const float* y_d  = (const float*)d_in[0];
    const float* y_gt = (const float*)d_in[1];
    float* out      = (float*)d_out;
    float* partials = (float*)d_ws;               // [NTILES]
    float* sums     = partials + NTILES;          // [N_IMG]

    wk_pass1<<<dim3(NTILES), dim3(256), 0, stream>>>(y_d, y_gt, out, partials);
    wk_reduce<<<dim3(N_IMG), dim3(64), 0, stream>>>(partials, sums);
    wk_pass2<<<dim3(2048), dim3(256), 0, stream>>>(out, sums);
}